// Round 1
// baseline (3869.000 us; speedup 1.0000x reference)
//
#include <hip/hip_runtime.h>

// ST-LSTM wavefront implementation, f32 baseline.
// Cells (r,t,j): r=rec layer(2), t=frame(25), j=bone(24).
// Dependency: (r,t-1,j), (r,t,j-1), (r-1,t,j)  ->  diagonal d = t+j+r, 49 steps.
// Each cell: z[256,640] = x@U + h_t@Wt + h_s@Ws + b   (K=128 each, 384 fused)
// then 5-gate LSTM epilogue (in-register, each thread owns all 5 gates).

#define Bn   256
#define TINn 49
#define TOUTn 25
#define NBn  24
#define Hn   128
#define HGn  640                      // 5*H
#define SLAB (NBn*Bn*Hn)              // 786432 floats, one [NB,B,H] state slab
#define OUTHALF (Bn*TOUTn*NBn*Hn)     // 19660800, h/c halves of d_out

__device__ __forceinline__ float sigm(float x){ return 1.0f/(1.0f + __expf(-x)); }
__device__ __forceinline__ float tanh_(float x){
  float xc = fminf(fmaxf(x, -10.0f), 10.0f);   // avoid inf/inf NaN; tanh(10)==1.0f in f32
  float e = __expf(2.0f*xc);
  return (e-1.0f)/(e+1.0f);
}

// row boundary means: s0h1 = mean_t(hidden) [rec0 temporal-h init, bone-major]
// r1h = (global + sum_t hidden)/50 [rec1 temporal-h init], r1c = s0c1 = mean_t(cell)
__global__ void precompute_rows(const float* __restrict__ hs, const float* __restrict__ cs,
                                const float* __restrict__ gt,
                                float* __restrict__ s0h1, float* __restrict__ s0c1,
                                float* __restrict__ r1h, float* __restrict__ r1c){
  int idx = blockIdx.x*256 + threadIdx.x;           // [j][b][h]
  int j = idx / (Bn*Hn);
  int rem = idx - j*(Bn*Hn);
  int b = rem / Hn;
  int h = rem - b*Hn;
  const float* ph = hs + ((size_t)b*TINn*NBn + j)*Hn + h;
  const float* pc = cs + ((size_t)b*TINn*NBn + j)*Hn + h;
  float sh = 0.f, sc = 0.f;
  #pragma unroll 7
  for (int t = 0; t < TINn; t++){ sh += ph[(size_t)t*NBn*Hn]; sc += pc[(size_t)t*NBn*Hn]; }
  s0h1[idx] = sh * (1.0f/49.0f);
  float rc  = sc * (1.0f/49.0f);
  s0c1[idx] = rc;
  r1c[idx]  = rc;
  r1h[idx]  = (gt[((size_t)b*NBn + j)*Hn + h] + sh) * (1.0f/50.0f);
}

// column boundary means over bones of the row means
__global__ void precompute_cols(const float* __restrict__ s0h1, const float* __restrict__ s0c1,
                                float* __restrict__ col_h, float* __restrict__ col_c){
  int idx = blockIdx.x*256 + threadIdx.x;           // [b][h]
  float a = 0.f, c = 0.f;
  #pragma unroll
  for (int j = 0; j < NBn; j++){ a += s0h1[j*(Bn*Hn) + idx]; c += s0c1[j*(Bn*Hn) + idx]; }
  col_h[idx] = a * (1.0f/24.0f);
  col_c[idx] = c * (1.0f/24.0f);
}

__device__ __forceinline__ int c0of(int d){   // rec0 cell count on diagonal d
  if (d < 0 || d > 47) return 0;
  return d <= 23 ? d + 1 : 48 - d;
}

// One wavefront diagonal. 8 block-tasks per cell: 2 batch halves x 4 hh-chunks.
// Block computes C[128 batch][5 gates][32 hh] over K=384, then gates in-register.
__global__ __launch_bounds__(256) void diag_kernel(int d,
    const float* __restrict__ p,  const float* __restrict__ U,
    const float* __restrict__ Wt, const float* __restrict__ Wsp,
    const float* __restrict__ bias,
    const float* __restrict__ col_h, const float* __restrict__ col_c,
    float* __restrict__ s0h, float* __restrict__ s0c,
    const float* __restrict__ r1h, const float* __restrict__ r1c,
    float* __restrict__ out)
{
  __shared__ float As[32][132];   // A-tile transposed: As[k][row]; 132 pad -> b128 reads ok
  __shared__ float Bs[32][160];   // B-tile: Bs[k][gate*32+hh]

  int n0   = c0of(d);
  int cell = blockIdx.x >> 3;
  int tile = blockIdx.x & 7;
  int r, t, j;
  if (cell < n0){ r = 0; t = (d > 23 ? d - 23 : 0) + cell; j = d - t; }
  else { int dd = d - 1; int c = cell - n0; r = 1; t = (dd > 23 ? dd - 23 : 0) + c; j = dd - t; }

  int bm0 = (tile & 1) * 128;
  int hc  = (tile >> 1) * 32;

  int parC = t & 1;         // parity of current frame (rec0 state buffers)
  int parP = (t + 1) & 1;   // previous frame parity

  const float* Ax;  int sx;   // GEMM input x
  const float* Aht; int sht;  // temporal h
  const float* Ahs; int shs;  // spatial h
  const float* Ct;  int sct;  // temporal c (epilogue)
  const float* Cs;  int scs;  // spatial c (epilogue)
  float* Oh; int soh;
  float* Oc; int soc;

  const float* outh = out;
  const float* outc = out + OUTHALF;

  if (r == 0){
    Ax  = p + ((size_t)t*NBn + j)*Hn;                 sx  = TOUTn*NBn*Hn;
    Aht = s0h + (size_t)parP*SLAB + (size_t)j*Bn*Hn;  sht = Hn;
    Ct  = s0c + (size_t)parP*SLAB + (size_t)j*Bn*Hn;  sct = Hn;
    Oh  = s0h + (size_t)parC*SLAB + (size_t)j*Bn*Hn;  soh = Hn;
    Oc  = s0c + (size_t)parC*SLAB + (size_t)j*Bn*Hn;  soc = Hn;
    if (j == 0){ Ahs = col_h; shs = Hn; Cs = col_c; scs = Hn; }
    else {
      Ahs = s0h + (size_t)parC*SLAB + (size_t)(j-1)*Bn*Hn; shs = Hn;
      Cs  = s0c + (size_t)parC*SLAB + (size_t)(j-1)*Bn*Hn; scs = Hn;
    }
  } else {
    Ax = s0h + (size_t)parC*SLAB + (size_t)j*Bn*Hn;   sx = Hn;   // rec0 output this frame
    if (t == 0){ Aht = r1h + (size_t)j*Bn*Hn; sht = Hn; Ct = r1c + (size_t)j*Bn*Hn; sct = Hn; }
    else {
      Aht = outh + ((size_t)(t-1)*NBn + j)*Hn; sht = TOUTn*NBn*Hn;
      Ct  = outc + ((size_t)(t-1)*NBn + j)*Hn; sct = TOUTn*NBn*Hn;
    }
    if (j == 0){ Ahs = col_h; shs = Hn; Cs = col_c; scs = Hn; }
    else {
      Ahs = outh + ((size_t)t*NBn + (j-1))*Hn; shs = TOUTn*NBn*Hn;
      Cs  = outc + ((size_t)t*NBn + (j-1))*Hn; scs = TOUTn*NBn*Hn;
    }
    Oh = out + ((size_t)t*NBn + j)*Hn;           soh = TOUTn*NBn*Hn;
    Oc = out + OUTHALF + ((size_t)t*NBn + j)*Hn; soc = TOUTn*NBn*Hn;
  }

  size_t woff = (size_t)(r*NBn + j)*Hn*HGn;
  const float* W0 = U   + woff;
  const float* W1 = Wt  + woff;
  const float* W2 = Wsp + woff;
  const float* bb = bias + (size_t)(r*NBn + j)*HGn;

  int tid = threadIdx.x;
  int ty = tid >> 3;    // 0..31: batch groups of 4
  int tx = tid & 7;     // 0..7 : hh groups of 4

  float acc[4][5][4];
  #pragma unroll
  for (int i=0;i<4;i++)
    #pragma unroll
    for (int g=0;g<5;g++)
      #pragma unroll
      for (int l=0;l<4;l++) acc[i][g][l] = 0.f;

  int arow  = tid >> 3;   // staging: A row group
  int akseg = tid & 7;    // staging: A k-segment (float4)
  int bkr   = tid >> 3;   // staging: B weight row
  int bc8   = tid & 7;    // staging: B col segment

  for (int cc = 0; cc < 12; cc++){          // 12 chunks of K=32 (x:0-3, ht:4-7, hs:8-11)
    int sel = cc >> 2;
    int k0  = (cc & 3) * 32;
    const float* Ab; int sA;
    if      (sel == 0){ Ab = Ax;  sA = sx;  }
    else if (sel == 1){ Ab = Aht; sA = sht; }
    else              { Ab = Ahs; sA = shs; }
    const float* Wb = (sel == 0) ? W0 : (sel == 1) ? W1 : W2;

    __syncthreads();
    // stage A transposed (so compute reads one b128 per k)
    #pragma unroll
    for (int q = 0; q < 4; q++){
      int row = arow + 32*q;
      const float4 v = *(const float4*)(Ab + (size_t)(bm0+row)*sA + k0 + akseg*4);
      As[akseg*4+0][row] = v.x;
      As[akseg*4+1][row] = v.y;
      As[akseg*4+2][row] = v.z;
      As[akseg*4+3][row] = v.w;
    }
    // stage B: 5 gate column-strips of 32
    #pragma unroll
    for (int g = 0; g < 5; g++){
      const float4 v = *(const float4*)(Wb + (size_t)(k0+bkr)*HGn + g*Hn + hc + bc8*4);
      *(float4*)&Bs[bkr][g*32 + bc8*4] = v;
    }
    __syncthreads();

    #pragma unroll
    for (int k = 0; k < 32; k++){
      float4 av = *(const float4*)&As[k][ty*4];
      float4 bv[5];
      #pragma unroll
      for (int g = 0; g < 5; g++) bv[g] = *(const float4*)&Bs[k][g*32 + tx*4];
      const float* ap = (const float*)&av;
      #pragma unroll
      for (int i = 0; i < 4; i++){
        float a = ap[i];
        #pragma unroll
        for (int g = 0; g < 5; g++){
          const float* bp = (const float*)&bv[g];
          #pragma unroll
          for (int l = 0; l < 4; l++) acc[i][g][l] = fmaf(a, bp[l], acc[i][g][l]);
        }
      }
    }
  }

  // epilogue: gates fully in-register (thread owns all 5 gates of its (b,hh))
  int hh0 = hc + tx*4;
  float4 bbv[5];
  #pragma unroll
  for (int g = 0; g < 5; g++) bbv[g] = *(const float4*)(bb + g*Hn + hh0);

  #pragma unroll
  for (int i = 0; i < 4; i++){
    int brow = bm0 + ty*4 + i;
    float4 ctv = *(const float4*)(Ct + (size_t)brow*sct + hh0);
    float4 csv = *(const float4*)(Cs + (size_t)brow*scs + hh0);
    const float* ctp = (const float*)&ctv;
    const float* csp = (const float*)&csv;
    float4 hv, cv;
    float* hp = (float*)&hv; float* cp = (float*)&cv;
    #pragma unroll
    for (int l = 0; l < 4; l++){
      float zi  = acc[i][0][l] + ((const float*)&bbv[0])[l];
      float zfs = acc[i][1][l] + ((const float*)&bbv[1])[l];
      float zft = acc[i][2][l] + ((const float*)&bbv[2])[l];
      float zo  = acc[i][3][l] + ((const float*)&bbv[3])[l];
      float zg  = acc[i][4][l] + ((const float*)&bbv[4])[l];
      float in_ = sigm(zi), fs = sigm(zfs), ft = sigm(zft), on = sigm(zo);
      float gg  = tanh_(zg);
      float c   = in_*gg + ft*ctp[l] + fs*csp[l];
      float h   = on * tanh_(c);
      cp[l] = c; hp[l] = h;
    }
    *(float4*)(Oh + (size_t)brow*soh + hh0) = hv;
    *(float4*)(Oc + (size_t)brow*soc + hh0) = cv;
  }
}

extern "C" void kernel_launch(void* const* d_in, const int* in_sizes, int n_in,
                              void* d_out, int out_size, void* d_ws, size_t ws_size,
                              hipStream_t stream){
  const float* hs  = (const float*)d_in[0];
  const float* cs  = (const float*)d_in[1];
  const float* gt  = (const float*)d_in[2];
  const float* p   = (const float*)d_in[3];
  const float* U   = (const float*)d_in[4];
  const float* Wt  = (const float*)d_in[5];
  const float* Wsp = (const float*)d_in[6];
  const float* bia = (const float*)d_in[7];
  float* out = (float*)d_out;
  float* ws  = (float*)d_ws;

  // workspace layout (floats): col_h, col_c, s0h[2 parity slabs], s0c[2], r1h, r1c
  float* col_h = ws;
  float* col_c = col_h + Bn*Hn;
  float* s0h   = col_c + Bn*Hn;
  float* s0c   = s0h + 2*(size_t)SLAB;
  float* r1h   = s0c + 2*(size_t)SLAB;
  float* r1c   = r1h + (size_t)SLAB;
  // total: 2*32768 + 6*786432 floats = 19.1 MB

  // boundary means; parity-1 slabs are the "frame -1" rec0 state
  precompute_rows<<<SLAB/256, 256, 0, stream>>>(hs, cs, gt, s0h + SLAB, s0c + SLAB, r1h, r1c);
  precompute_cols<<<(Bn*Hn)/256, 256, 0, stream>>>(s0h + SLAB, s0c + SLAB, col_h, col_c);

  for (int d = 0; d <= 48; d++){
    int n0 = (d <= 47) ? (d <= 23 ? d + 1 : 48 - d) : 0;
    int n1 = (d >= 1)  ? ((d-1) <= 23 ? d : 49 - d) : 0;
    int ncells = n0 + n1;
    diag_kernel<<<ncells*8, 256, 0, stream>>>(d, p, U, Wt, Wsp, bia,
                                              col_h, col_c, s0h, s0c, r1h, r1c, out);
  }
}

// Round 2
// 2206.384 us; speedup vs baseline: 1.7535x; 1.7535x over previous
//
#include <hip/hip_runtime.h>

// ST-LSTM wavefront, bf16 hi/lo split MFMA version.
// Cells (r,t,j): diagonal d = t+j+r, 49 sequential launches.
// Per cell: z[256,640] = [x|h_t|h_s][256,384] @ W[384,640] + b, 5-gate epilogue.
// GEMM on matrix cores via 4-term bf16 split: (Ah+Al)@(Wh+Wl), f32-equivalent accuracy.

#define Bn    256
#define TINn  49
#define TOUTn 25
#define NBn   24
#define Hn    128
#define HGn   640
#define SLAB  (NBn*Bn*Hn)             // 786432 floats
#define OUTHALF (Bn*TOUTn*NBn*Hn)     // h/c halves of d_out
#define WPK_ELEMS ((size_t)48*12*640*32)   // per hi/lo tensor, halfs

typedef __attribute__((ext_vector_type(8))) short     bf16x8;
typedef __attribute__((ext_vector_type(4))) float     f32x4;
typedef __attribute__((ext_vector_type(4))) unsigned short u16x4;

__device__ __forceinline__ float sigm(float x){ return 1.0f/(1.0f + __expf(-x)); }
__device__ __forceinline__ float tanh_(float x){
  float xc = fminf(fmaxf(x, -10.0f), 10.0f);
  float e = __expf(2.0f*xc);
  return (e-1.0f)/(e+1.0f);
}
__device__ __forceinline__ unsigned short f2bf(float x){
  unsigned int u = __float_as_uint(x);
  unsigned int r = (u + 0x7FFFu + ((u >> 16) & 1u)) >> 16;
  return (unsigned short)r;
}
__device__ __forceinline__ float bf2f(unsigned short h){
  return __uint_as_float(((unsigned int)h) << 16);
}
__device__ __forceinline__ float4 add4(float4 a, float4 b){
  return make_float4(a.x+b.x, a.y+b.y, a.z+b.z, a.w+b.w);
}
__device__ __forceinline__ float4 scl4(float4 a, float s){
  return make_float4(a.x*s, a.y*s, a.z*s, a.w*s);
}

// ---- boundary means (float4-vectorized) ----
__global__ void precompute_rows(const float4* __restrict__ hs, const float4* __restrict__ cs,
                                const float4* __restrict__ gt,
                                float4* __restrict__ s0h1, float4* __restrict__ s0c1,
                                float4* __restrict__ r1h, float4* __restrict__ r1c){
  int v = blockIdx.x*256 + threadIdx.x;           // [j][b][h4], SLAB/4 total
  int h4 = v & 31; int b = (v >> 5) & 255; int j = v >> 13;
  const float4* ph = hs + ((size_t)b*TINn*NBn + j)*32 + h4;
  const float4* pc = cs + ((size_t)b*TINn*NBn + j)*32 + h4;
  float4 sh = make_float4(0,0,0,0), sc = make_float4(0,0,0,0);
  #pragma unroll 7
  for (int t = 0; t < TINn; t++){
    sh = add4(sh, ph[(size_t)t*NBn*32]);
    sc = add4(sc, pc[(size_t)t*NBn*32]);
  }
  s0h1[v] = scl4(sh, 1.0f/49.0f);
  float4 rc = scl4(sc, 1.0f/49.0f);
  s0c1[v] = rc;
  r1c[v]  = rc;
  float4 g = gt[((size_t)b*NBn + j)*32 + h4];
  r1h[v]  = scl4(add4(g, sh), 1.0f/50.0f);
}

__global__ void precompute_cols(const float4* __restrict__ s0h1, const float4* __restrict__ s0c1,
                                float4* __restrict__ col_h, float4* __restrict__ col_c){
  int v = blockIdx.x*256 + threadIdx.x;           // [b][h4]
  float4 a = make_float4(0,0,0,0), c = make_float4(0,0,0,0);
  #pragma unroll
  for (int j = 0; j < NBn; j++){
    a = add4(a, s0h1[(size_t)j*8192 + v]);
    c = add4(c, s0c1[(size_t)j*8192 + v]);
  }
  col_h[v] = scl4(a, 1.0f/24.0f);
  col_c[v] = scl4(c, 1.0f/24.0f);
}

// ---- weight transpose + bf16 hi/lo split ----
// dst layout: [cell 48][kstep 12][col 640][k 32] halfs; kstep = mat*4 + kq
__global__ __launch_bounds__(256) void convert_weights(
    const float* __restrict__ U, const float* __restrict__ Wt, const float* __restrict__ Ws,
    unsigned short* __restrict__ Whi, unsigned short* __restrict__ Wlo){
  __shared__ float T[32][65];
  int blk = blockIdx.x;                 // ((cell*3)+mat)*4 + kq
  int kq = blk & 3; int rem = blk >> 2; int mat = rem % 3; int cell = rem / 3;
  const float* src = (mat==0 ? U : mat==1 ? Wt : Ws) + (size_t)cell*128*HGn;
  int t = threadIdx.x;
  for (int c0 = 0; c0 < HGn; c0 += 64){
    __syncthreads();
    #pragma unroll
    for (int it = 0; it < 8; it++){
      int e = t + 256*it; int kk = e >> 6; int cc = e & 63;
      T[kk][cc] = src[(size_t)(kq*32 + kk)*HGn + c0 + cc];
    }
    __syncthreads();
    #pragma unroll
    for (int it = 0; it < 8; it++){
      int e = t + 256*it; int cc = e >> 5; int kk = e & 31;
      float x = T[kk][cc];
      unsigned short hi = f2bf(x);
      unsigned short lo = f2bf(x - bf2f(hi));
      size_t idx = ((size_t)(cell*12 + mat*4 + kq)*HGn + (c0 + cc))*32 + kk;
      Whi[idx] = hi; Wlo[idx] = lo;
    }
  }
}

__device__ __host__ __forceinline__ int c0of(int d){
  if (d < 0 || d > 47) return 0;
  return d <= 23 ? d + 1 : 48 - d;
}

// ---- MFMA wavefront diagonal ----
// 8 blocks/cell: 2 batch halves x 4 hh-chunks. Block = 4 waves.
// Block tile: 128 batch x (5 gates x 32 hh). Wave: 64 batch x (5 gates x 16 hh).
__global__ __launch_bounds__(256) void diag_kernel(int d,
    const float* __restrict__ p,
    const unsigned short* __restrict__ WhiG, const unsigned short* __restrict__ WloG,
    const float* __restrict__ bias,
    const float* __restrict__ col_h, const float* __restrict__ col_c,
    float* __restrict__ s0h, float* __restrict__ s0c,
    const float* __restrict__ r1h, const float* __restrict__ r1c,
    float* __restrict__ out)
{
  // padded stride 40 halfs (80B): 16-lane b128 reads land 2-way per bank (free, m136)
  __shared__ unsigned short AsH[128*40], AsL[128*40];
  __shared__ unsigned short BsH[160*40], BsL[160*40];

  int n0   = c0of(d);
  int cell = blockIdx.x >> 3;
  int tile = blockIdx.x & 7;
  int r, t, j;
  if (cell < n0){ r = 0; t = (d > 23 ? d - 23 : 0) + cell; j = d - t; }
  else { int dd = d - 1; int c = cell - n0; r = 1; t = (dd > 23 ? dd - 23 : 0) + c; j = dd - t; }

  int bm0 = (tile & 1) * 128;     // batch half
  int hc  = (tile >> 1) * 32;     // hh chunk

  int parC = t & 1;
  int parP = (t + 1) & 1;

  const float* Ax;  int sx;
  const float* Aht; int sht;
  const float* Ahs; int shs;
  const float* Ct;  int sct;
  const float* Cs;  int scs;
  float* Oh; int soh;
  float* Oc; int soc;

  const float* outh = out;
  const float* outc = out + OUTHALF;

  if (r == 0){
    Ax  = p + ((size_t)t*NBn + j)*Hn;                 sx  = TOUTn*NBn*Hn;
    Aht = s0h + (size_t)parP*SLAB + (size_t)j*Bn*Hn;  sht = Hn;
    Ct  = s0c + (size_t)parP*SLAB + (size_t)j*Bn*Hn;  sct = Hn;
    Oh  = s0h + (size_t)parC*SLAB + (size_t)j*Bn*Hn;  soh = Hn;
    Oc  = s0c + (size_t)parC*SLAB + (size_t)j*Bn*Hn;  soc = Hn;
    if (j == 0){ Ahs = col_h; shs = Hn; Cs = col_c; scs = Hn; }
    else {
      Ahs = s0h + (size_t)parC*SLAB + (size_t)(j-1)*Bn*Hn; shs = Hn;
      Cs  = s0c + (size_t)parC*SLAB + (size_t)(j-1)*Bn*Hn; scs = Hn;
    }
  } else {
    Ax = s0h + (size_t)parC*SLAB + (size_t)j*Bn*Hn;   sx = Hn;
    if (t == 0){ Aht = r1h + (size_t)j*Bn*Hn; sht = Hn; Ct = r1c + (size_t)j*Bn*Hn; sct = Hn; }
    else {
      Aht = outh + ((size_t)(t-1)*NBn + j)*Hn; sht = TOUTn*NBn*Hn;
      Ct  = outc + ((size_t)(t-1)*NBn + j)*Hn; sct = TOUTn*NBn*Hn;
    }
    if (j == 0){ Ahs = col_h; shs = Hn; Cs = col_c; scs = Hn; }
    else {
      Ahs = outh + ((size_t)t*NBn + (j-1))*Hn; shs = TOUTn*NBn*Hn;
      Cs  = outc + ((size_t)t*NBn + (j-1))*Hn; scs = TOUTn*NBn*Hn;
    }
    Oh = out + ((size_t)t*NBn + j)*Hn;           soh = TOUTn*NBn*Hn;
    Oc = out + OUTHALF + ((size_t)t*NBn + j)*Hn; soc = TOUTn*NBn*Hn;
  }

  int cellIdx = r*NBn + j;
  const float* bb = bias + (size_t)cellIdx*HGn;

  int tid  = threadIdx.x;
  int lane = tid & 63;
  int wv   = tid >> 6;
  int wr   = wv >> 1;       // batch 64-half within block tile
  int wc   = wv & 1;        // hh 16-slice
  int lrow = lane & 15;
  int lgrp = lane >> 4;

  int tA_row  = tid >> 1;            // 0..127
  int tA_seg0 = (tid & 1) * 4;       // float4 segs seg0..seg0+3

  f32x4 acc[4][5];
  #pragma unroll
  for (int m = 0; m < 4; m++)
    #pragma unroll
    for (int g = 0; g < 5; g++) acc[m][g] = (f32x4){0.f,0.f,0.f,0.f};

  for (int cc = 0; cc < 12; cc++){
    int sel = cc >> 2;
    int kl0 = (cc & 3) * 32;
    const float* Ab; int sA;
    if      (sel == 0){ Ab = Ax;  sA = sx;  }
    else if (sel == 1){ Ab = Aht; sA = sht; }
    else              { Ab = Ahs; sA = shs; }

    __syncthreads();

    // stage A: f32 -> bf16 hi/lo into LDS [row][40]
    #pragma unroll
    for (int s = 0; s < 4; s++){
      int seg = tA_seg0 + s;
      const float4 v = *(const float4*)(Ab + (size_t)(bm0 + tA_row)*sA + kl0 + seg*4);
      unsigned short h0 = f2bf(v.x), h1 = f2bf(v.y), h2 = f2bf(v.z), h3 = f2bf(v.w);
      u16x4 hv = {h0, h1, h2, h3};
      u16x4 lv = {f2bf(v.x - bf2f(h0)), f2bf(v.y - bf2f(h1)),
                  f2bf(v.z - bf2f(h2)), f2bf(v.w - bf2f(h3))};
      *(u16x4*)&AsH[tA_row*40 + seg*4] = hv;
      *(u16x4*)&AsL[tA_row*40 + seg*4] = lv;
    }

    // stage B: packed bf16 weights, 16B chunks into [col_local 160][40]
    size_t wBase = (size_t)(cellIdx*12 + cc)*HGn*32;
    #pragma unroll
    for (int q = 0; q < 5; q++){
      int sid = tid + 256*q;               // 0..1279
      int ten = sid >= 640;
      int s2  = sid - ten*640;
      int cl  = s2 >> 2;                   // 0..159
      int slot= s2 & 3;
      int gate= cl >> 5;
      int hh  = cl & 31;
      const unsigned short* srcW = (ten ? WloG : WhiG)
          + wBase + (size_t)(gate*128 + hc + hh)*32 + slot*8;
      int4 v = *(const int4*)srcW;
      unsigned short* dst = (ten ? BsL : BsH) + cl*40 + slot*8;
      *(int4*)dst = v;
    }

    __syncthreads();

    // compute: per wave 5 B-frag pairs, 4 A-frag pairs, 80 MFMA
    bf16x8 bh[5], bl[5];
    #pragma unroll
    for (int g = 0; g < 5; g++){
      int co = (g*32 + wc*16 + lrow)*40 + lgrp*8;
      bh[g] = *(const bf16x8*)&BsH[co];
      bl[g] = *(const bf16x8*)&BsL[co];
    }
    #pragma unroll
    for (int m = 0; m < 4; m++){
      int ao = (wr*64 + m*16 + lrow)*40 + lgrp*8;
      bf16x8 ah = *(const bf16x8*)&AsH[ao];
      bf16x8 al = *(const bf16x8*)&AsL[ao];
      #pragma unroll
      for (int g = 0; g < 5; g++){
        acc[m][g] = __builtin_amdgcn_mfma_f32_16x16x32_bf16(ah, bh[g], acc[m][g], 0, 0, 0);
        acc[m][g] = __builtin_amdgcn_mfma_f32_16x16x32_bf16(ah, bl[g], acc[m][g], 0, 0, 0);
        acc[m][g] = __builtin_amdgcn_mfma_f32_16x16x32_bf16(al, bh[g], acc[m][g], 0, 0, 0);
        acc[m][g] = __builtin_amdgcn_mfma_f32_16x16x32_bf16(al, bl[g], acc[m][g], 0, 0, 0);
      }
    }
  }

  // epilogue: thread owns all 5 gates at (16 rows, 1 hh)
  int hhg = hc + wc*16 + lrow;
  float b5[5];
  #pragma unroll
  for (int g = 0; g < 5; g++) b5[g] = bb[g*Hn + hhg];

  #pragma unroll
  for (int m = 0; m < 4; m++){
    #pragma unroll
    for (int reg = 0; reg < 4; reg++){
      int brow = bm0 + wr*64 + m*16 + lgrp*4 + reg;
      float zi  = acc[m][0][reg] + b5[0];
      float zfs = acc[m][1][reg] + b5[1];
      float zft = acc[m][2][reg] + b5[2];
      float zo  = acc[m][3][reg] + b5[3];
      float zg  = acc[m][4][reg] + b5[4];
      float ct  = Ct[(size_t)brow*sct + hhg];
      float csv = Cs[(size_t)brow*scs + hhg];
      float in_ = sigm(zi), fs = sigm(zfs), ft = sigm(zft), on = sigm(zo);
      float gg  = tanh_(zg);
      float c   = in_*gg + ft*ct + fs*csv;
      float h   = on * tanh_(c);
      Oh[(size_t)brow*soh + hhg] = h;
      Oc[(size_t)brow*soc + hhg] = c;
    }
  }
}

extern "C" void kernel_launch(void* const* d_in, const int* in_sizes, int n_in,
                              void* d_out, int out_size, void* d_ws, size_t ws_size,
                              hipStream_t stream){
  const float* hs  = (const float*)d_in[0];
  const float* cs  = (const float*)d_in[1];
  const float* gt  = (const float*)d_in[2];
  const float* p   = (const float*)d_in[3];
  const float* U   = (const float*)d_in[4];
  const float* Wt  = (const float*)d_in[5];
  const float* Wsp = (const float*)d_in[6];
  const float* bia = (const float*)d_in[7];
  float* out = (float*)d_out;
  float* ws  = (float*)d_ws;

  // ws layout: col_h, col_c (32768 ea) | s0h[2], s0c[2] slabs | r1h, r1c | Whi, Wlo (bf16)
  float* col_h = ws;
  float* col_c = col_h + Bn*Hn;
  float* s0h   = col_c + Bn*Hn;
  float* s0c   = s0h + 2*(size_t)SLAB;
  float* r1h   = s0c + 2*(size_t)SLAB;
  float* r1c   = r1h + (size_t)SLAB;
  unsigned short* Whi = (unsigned short*)(r1c + (size_t)SLAB);
  unsigned short* Wlo = Whi + WPK_ELEMS;
  // total ~66.3 MB

  convert_weights<<<48*3*4, 256, 0, stream>>>(U, Wt, Wsp, Whi, Wlo);
  precompute_rows<<<SLAB/4/256, 256, 0, stream>>>(
      (const float4*)hs, (const float4*)cs, (const float4*)gt,
      (float4*)(s0h + SLAB), (float4*)(s0c + SLAB), (float4*)r1h, (float4*)r1c);
  precompute_cols<<<(Bn*Hn)/4/256, 256, 0, stream>>>(
      (const float4*)(s0h + SLAB), (const float4*)(s0c + SLAB),
      (float4*)col_h, (float4*)col_c);

  for (int d = 0; d <= 48; d++){
    int n0 = c0of(d);
    int n1 = c0of(d-1);
    int ncells = n0 + n1;
    diag_kernel<<<ncells*8, 256, 0, stream>>>(d, p, Whi, Wlo, bia,
                                              col_h, col_c, s0h, s0c, r1h, r1c, out);
  }
}